// Round 3
// baseline (318.449 us; speedup 1.0000x reference)
//
#include <hip/hip_runtime.h>

// B=32, T=512, D=512, L=2048. x:(B,T,D) f32, durations:(B,T) f32.
// d_out = aligned (B,L,D) f32  ||  attn (B,T,L) f32.
//
// attn column l = softmax_t of -0.2*(l-start_t)^2. Terms more than
// sqrt(smin^2+200) frames from l are < e^-40 of the max term (denom >= 1),
// i.e. < 4.3e-18 -> exact 0 in fp32 outputs and invisible in the denom.
//
// R8 (this round): split into 3 kernels, each at its own roofline regime.
//  K1 cumsum_starts: scan durations -> starts (ws), tiny.
//  K3 aligned_gather: banded gather, LT=32 (2048 blocks, 8 rounds/CU for
//     load balance), ONE band walk per wave (R7 walked twice), XCD swizzle.
//  K2 attn_write: uniform dense streaming: per-block l-tables in LDS built
//     once, params hoisted to regs, then 32 rows of pure float4 NT stores.
//     No bands, no imbalance -> fill-like write BW.

typedef float v4f __attribute__((ext_vector_type(4)));

static constexpr int Bc = 32;
static constexpr int Tc = 512;
static constexpr int Dc = 512;
static constexpr int Lc = 2048;
static constexpr float SIGMA = 0.2f;
static constexpr float CUT2 = 200.0f;     // 40/SIGMA

// K1: starts[b][t] = exclusive cumsum of durations along t.
__global__ void cumsum_starts(const float* __restrict__ dur,
                              float* __restrict__ starts) {
  const int b = blockIdx.x;
  const int t = threadIdx.x; // blockDim.x == Tc
  __shared__ float buf[Tc];
  float d = dur[(size_t)b * Tc + t];
  float v = d;
  buf[t] = v;
  __syncthreads();
  for (int off = 1; off < Tc; off <<= 1) {
    float add = (t >= off) ? buf[t - off] : 0.0f;
    __syncthreads();
    v += add;
    buf[t] = v;
    __syncthreads();
  }
  starts[(size_t)b * Tc + t] = v - d;
}

// K3: aligned gather. One 256-thread block per (b, 32-frame tile).
__global__ void __launch_bounds__(256, 4)
aligned_gather(const float* __restrict__ x,
               const float* __restrict__ starts,
               float* __restrict__ aligned) {
  const int tid = threadIdx.x;
  const int bid = blockIdx.x;
  // XCD-chunked swizzle: 2048 blocks, 8 XCDs -> 256 per XCD = 4 consecutive b.
  const int swz = (bid & 7) * 256 + (bid >> 3);
  const int b = swz >> 6;                   // 64 tiles per b
  const int l0 = (swz & 63) * 32;

  __shared__ float sbS[Tc];
  __shared__ float ngS[32], ivS[32];
  __shared__ int T0w[4], T1w[4];

  if (tid < 4) { T0w[tid] = Tc; T1w[tid] = 0; }
  sbS[tid]       = starts[(size_t)b * Tc + tid];
  sbS[tid + 256] = starts[(size_t)b * Tc + tid + 256];
  __syncthreads();

  // Per-l setup (32 threads): nearest start, band, banded denom.
  if (tid < 32) {
    const float fl = (float)(l0 + tid);
    int lo = 0, hi = Tc;
    while (lo < hi) { int mid = (lo + hi) >> 1; if (sbS[mid] <= fl) lo = mid + 1; else hi = mid; }
    float smin = fl - sbS[lo - 1];          // sbS[0]=0 <= fl -> lo >= 1
    if (lo < Tc) smin = fminf(smin, sbS[lo] - fl);
    const float smin2 = smin * smin;
    const float negam = SIGMA * smin2;
    const float smax = sqrtf(smin2 + CUT2);
    const float loV = fl - smax, hiV = fl + smax;
    int a = 0, c = lo;
    while (a < c) { int mid = (a + c) >> 1; if (sbS[mid] < loV) a = mid + 1; else c = mid; }
    const int bt0 = a;
    a = lo; c = Tc;
    while (a < c) { int mid = (a + c) >> 1; if (sbS[mid] <= hiV) a = mid + 1; else c = mid; }
    const int bt1 = a;
    float denom = 0.0f;
    for (int t = bt0; t < bt1; ++t) {
      const float s = fl - sbS[t];
      denom += __expf(negam - SIGMA * s * s);  // <= 1, max term = 1
    }
    ngS[tid] = negam;
    ivS[tid] = 1.0f / denom;
    atomicMin(&T0w[tid >> 3], bt0);
    atomicMax(&T1w[tid >> 3], bt1);
  }
  __syncthreads();

  // Wave w owns l [8w, 8w+8) x full D. ONE walk of the wave-union band.
  {
    const int w = tid >> 6;
    const int lane = tid & 63;
    const int Tb0 = T0w[w], Tb1 = T1w[w];
    const float4* __restrict__ xb = (const float4*)(x + (size_t)b * Tc * Dc);
    float negam_r[8];
    #pragma unroll
    for (int li = 0; li < 8; ++li) negam_r[li] = ngS[8 * w + li];
    const float flb = (float)(l0 + 8 * w);
    float4 acc[8][2] = {};
    for (int t = Tb0; t < Tb1; ++t) {
      const float4 r0 = xb[(size_t)t * (Dc / 4) + lane];
      const float4 r1 = xb[(size_t)t * (Dc / 4) + 64 + lane];
      const float d0 = flb - sbS[t];
      #pragma unroll
      for (int li = 0; li < 8; ++li) {
        const float s = d0 + (float)li;
        const float wgt = __expf(negam_r[li] - SIGMA * s * s);
        acc[li][0].x += wgt * r0.x; acc[li][0].y += wgt * r0.y;
        acc[li][0].z += wgt * r0.z; acc[li][0].w += wgt * r0.w;
        acc[li][1].x += wgt * r1.x; acc[li][1].y += wgt * r1.y;
        acc[li][1].z += wgt * r1.z; acc[li][1].w += wgt * r1.w;
      }
    }
    #pragma unroll
    for (int li = 0; li < 8; ++li) {
      const float inv = ivS[8 * w + li];
      v4f* __restrict__ ab =
          (v4f*)(aligned + ((size_t)b * Lc + l0 + 8 * w + li) * Dc);
      v4f v0 = { acc[li][0].x * inv, acc[li][0].y * inv,
                 acc[li][0].z * inv, acc[li][0].w * inv };
      v4f v1 = { acc[li][1].x * inv, acc[li][1].y * inv,
                 acc[li][1].z * inv, acc[li][1].w * inv };
      __builtin_nontemporal_store(v0, ab + lane);      // 1KB/instr, contiguous
      __builtin_nontemporal_store(v1, ab + 64 + lane);
    }
  }
}

// K2: dense attn streaming write. One 256-thread block per (b, 32 t-rows).
// Per-block l-tables (negam/inv/thr for all 2048 l) in LDS; per-thread
// column params hoisted to regs; then 32 rows of pure float4 NT stores.
__global__ void __launch_bounds__(256)
attn_write(const float* __restrict__ starts,
           float* __restrict__ attn) {
  const int tid = threadIdx.x;
  const int b = blockIdx.x >> 4;            // 32 b x 16 chunks
  const int chunk = blockIdx.x & 15;        // 32 rows each

  __shared__ float sbS[Tc];
  __shared__ __align__(16) float ngS[Lc];
  __shared__ __align__(16) float ivS[Lc];
  __shared__ __align__(16) float thS[Lc];

  sbS[tid]       = starts[(size_t)b * Tc + tid];
  sbS[tid + 256] = starts[(size_t)b * Tc + tid + 256];
  __syncthreads();

  // l-tables: 8 l's per thread.
  #pragma unroll
  for (int i = 0; i < 8; ++i) {
    const int l = tid + 256 * i;
    const float fl = (float)l;
    int lo = 0, hi = Tc;
    while (lo < hi) { int mid = (lo + hi) >> 1; if (sbS[mid] <= fl) lo = mid + 1; else hi = mid; }
    float smin = fl - sbS[lo - 1];
    if (lo < Tc) smin = fminf(smin, sbS[lo] - fl);
    const float smin2 = smin * smin;
    const float negam = SIGMA * smin2;
    const float smax = sqrtf(smin2 + CUT2);
    const float loV = fl - smax, hiV = fl + smax;
    int a = 0, c = lo;
    while (a < c) { int mid = (a + c) >> 1; if (sbS[mid] < loV) a = mid + 1; else c = mid; }
    const int bt0 = a;
    a = lo; c = Tc;
    while (a < c) { int mid = (a + c) >> 1; if (sbS[mid] <= hiV) a = mid + 1; else c = mid; }
    const int bt1 = a;
    float denom = 0.0f;
    for (int t = bt0; t < bt1; ++t) {
      const float s = fl - sbS[t];
      denom += __expf(negam - SIGMA * s * s);
    }
    ngS[l] = negam;
    ivS[l] = 1.0f / denom;
    thS[l] = smin2 + CUT2;
  }
  __syncthreads();

  // Stream 32 rows. Thread owns columns [4*tid,4*tid+4) and [4*(tid+256),...).
  const int c0 = 4 * tid, c1 = 4 * (tid + 256);
  const v4f ng0 = *(const v4f*)&ngS[c0], ng1 = *(const v4f*)&ngS[c1];
  const v4f iv0 = *(const v4f*)&ivS[c0], iv1 = *(const v4f*)&ivS[c1];
  const v4f th0 = *(const v4f*)&thS[c0], th1 = *(const v4f*)&thS[c1];
  const float f0 = (float)c0, f1 = (float)c1;
  float* __restrict__ ap = attn + (size_t)b * Tc * Lc;
  for (int r = 0; r < 32; ++r) {
    const int t = chunk * 32 + r;
    const float sb = sbS[t];
    v4f v0, v1;
    #pragma unroll
    for (int j = 0; j < 4; ++j) {
      const float s0 = f0 + (float)j - sb;
      const float ss0 = s0 * s0;
      v0[j] = (ss0 <= th0[j]) ? __expf(ng0[j] - SIGMA * ss0) * iv0[j] : 0.0f;
      const float s1 = f1 + (float)j - sb;
      const float ss1 = s1 * s1;
      v1[j] = (ss1 <= th1[j]) ? __expf(ng1[j] - SIGMA * ss1) * iv1[j] : 0.0f;
    }
    __builtin_nontemporal_store(v0, (v4f*)(ap + (size_t)t * Lc + c0));
    __builtin_nontemporal_store(v1, (v4f*)(ap + (size_t)t * Lc + c1));
  }
}

extern "C" void kernel_launch(void* const* d_in, const int* in_sizes, int n_in,
                              void* d_out, int out_size, void* d_ws, size_t ws_size,
                              hipStream_t stream) {
  const float* x   = (const float*)d_in[0];
  const float* dur = (const float*)d_in[1];

  float* aligned = (float*)d_out;                        // B*L*D
  float* attn    = (float*)d_out + (size_t)Bc * Lc * Dc; // B*T*L
  float* starts  = (float*)d_ws;                         // B*T

  cumsum_starts<<<Bc, Tc, 0, stream>>>(dur, starts);
  aligned_gather<<<Bc * (Lc / 32), 256, 0, stream>>>(x, starts, aligned);
  attn_write<<<Bc * 16, 256, 0, stream>>>(starts, attn);
}

// Round 4
// 301.174 us; speedup vs baseline: 1.0574x; 1.0574x over previous
//
#include <hip/hip_runtime.h>

// B=32, T=512, D=512, L=2048. x:(B,T,D) f32, durations:(B,T) f32.
// d_out = aligned (B,L,D) f32  ||  attn (B,T,L) f32.
//
// attn column l = softmax_t of -0.2*(l-start_t)^2. Terms more than
// sqrt(smin^2+200) frames from l are < e^-40 of the max term (denom >= 1),
// i.e. < 4.3e-18 -> exact 0 in fp32 outputs and invisible in the denom.
//
// R7: single fused dispatch (in-block shfl scan of durations; no ws) = 298us.
// R8: 3-kernel split REGRESSED (+20us launch/serialization) but proved the
//     LT=32 gather geometry.
// R9 (this round): fused monolith + LT=32 geometry.
//   - 2048 blocks (one per (b, 32-l tile)), XCD-chunked swizzle (256 blocks
//     = 4 consecutive b per XCD; 4.2MB of x ~ one XCD L2).
//   - Wave owns 8 l's, ONE walk of its ~9-token union band (R7: 2 walks of
//     ~11 tokens for 16 l's) -> 2.4x fewer gather iterations per wave.
//   - 8 blocks/CU issued at 4/CU occupancy -> 2 rounds, tail smoothing.
//   - Phase C: 32-l columns, 8 rows x 128B (=cache line) per instruction.

typedef float v4f __attribute__((ext_vector_type(4)));

static constexpr int Bc = 32;
static constexpr int Tc = 512;
static constexpr int Dc = 512;
static constexpr int Lc = 2048;
static constexpr int LT = 32;             // frames per block
static constexpr float SIGMA = 0.2f;
static constexpr float CUT2 = 200.0f;     // 40/SIGMA

// One 256-thread block per (b, 32-frame tile).
__global__ void __launch_bounds__(256, 4)
soft_align(const float* __restrict__ x,
           const float* __restrict__ dur,
           float* __restrict__ aligned,
           float* __restrict__ attn) {
  const int tid = threadIdx.x;
  const int bid = blockIdx.x;
  // XCD-chunked swizzle: 2048 blocks, 8 XCDs -> 256 per XCD = 4 consecutive b.
  const int swz = (bid & 7) * 256 + (bid >> 3);
  const int b = swz >> 6;                   // 64 tiles per b
  const int tile = swz & 63;
  const int l0 = tile * LT;

  __shared__ float sbS[Tc];                 // token start offsets
  __shared__ __align__(16) float ngS[LT];   // SIGMA*smin^2 per l
  __shared__ __align__(16) float ivS[LT];   // 1/denom per l
  __shared__ __align__(16) float thS[LT];   // smin^2 + 200 per l
  __shared__ int T0w[4], T1w[4];            // per-wave union band
  __shared__ float wsumS[4];                // per-wave duration sums (scan)

  // Fused exclusive cumsum of durations -> sbS.
  // Wave w scans elements [128w, 128w+128), 2 per lane, shfl_up scan.
  {
    const int w = tid >> 6, lane = tid & 63;
    const int e0 = 128 * w + 2 * lane;
    const float2 dv = *(const float2*)(dur + (size_t)b * Tc + e0);
    const float p = dv.x + dv.y;
    float s = p;
    #pragma unroll
    for (int off = 1; off < 64; off <<= 1) {
      const float v = __shfl_up(s, off);
      if (lane >= off) s += v;
    }
    if (lane == 63) wsumS[w] = s;
    if (tid < 4) { T0w[tid] = Tc; T1w[tid] = 0; }
    __syncthreads();
    float prefix = 0.0f;
    #pragma unroll
    for (int i = 0; i < 3; ++i) prefix += (i < w) ? wsumS[i] : 0.0f;
    sbS[e0]     = prefix + s - p;            // excl. prefix of e0
    sbS[e0 + 1] = prefix + s - dv.y;         // excl. prefix of e0+1
  }
  __syncthreads();

  // Per-l setup (32 threads): nearest start (exact softmax max), band
  // bounds by binary search, banded denom (exact in fp32).
  if (tid < LT) {
    const float fl = (float)(l0 + tid);
    int lo = 0, hi = Tc;
    while (lo < hi) { int mid = (lo + hi) >> 1; if (sbS[mid] <= fl) lo = mid + 1; else hi = mid; }
    float smin = fl - sbS[lo - 1];          // sbS[0]=0 <= fl -> lo >= 1
    if (lo < Tc) smin = fminf(smin, sbS[lo] - fl);
    const float smin2 = smin * smin;
    const float negam = SIGMA * smin2;
    const float smax = sqrtf(smin2 + CUT2);
    const float loV = fl - smax, hiV = fl + smax;
    int a = 0, c = lo;
    while (a < c) { int mid = (a + c) >> 1; if (sbS[mid] < loV) a = mid + 1; else c = mid; }
    const int bt0 = a;                      // first t with sbS[t] >= loV
    a = lo; c = Tc;
    while (a < c) { int mid = (a + c) >> 1; if (sbS[mid] <= hiV) a = mid + 1; else c = mid; }
    const int bt1 = a;                      // first t with sbS[t] > hiV
    float denom = 0.0f;
    for (int t = bt0; t < bt1; ++t) {
      const float s = fl - sbS[t];
      denom += __expf(negam - SIGMA * s * s);  // <= 1, max term = 1
    }
    ngS[tid] = negam;
    ivS[tid] = 1.0f / denom;
    thS[tid] = smin2 + CUT2;
    atomicMin(&T0w[tid >> 3], bt0);
    atomicMax(&T1w[tid >> 3], bt1);
  }
  __syncthreads();

  // Phase B: aligned gather. Wave w owns l [8w, 8w+8) x full D.
  // ONE walk of the wave-union band; lane reads 2 distinct float4 of row t
  // (2KB/wave-instr-pair, full coalescing).
  {
    const int w = tid >> 6;
    const int lane = tid & 63;
    const int Tb0 = T0w[w], Tb1 = T1w[w];
    const float4* __restrict__ xb = (const float4*)(x + (size_t)b * Tc * Dc);
    float negam_r[8];
    #pragma unroll
    for (int li = 0; li < 8; ++li) negam_r[li] = ngS[8 * w + li];
    const float flb = (float)(l0 + 8 * w);
    float4 acc[8][2] = {};
    for (int t = Tb0; t < Tb1; ++t) {
      const float4 r0 = xb[(size_t)t * (Dc / 4) + lane];
      const float4 r1 = xb[(size_t)t * (Dc / 4) + 64 + lane];
      const float d0 = flb - sbS[t];
      #pragma unroll
      for (int li = 0; li < 8; ++li) {
        const float s = d0 + (float)li;
        const float wgt = __expf(negam_r[li] - SIGMA * s * s);
        acc[li][0].x += wgt * r0.x; acc[li][0].y += wgt * r0.y;
        acc[li][0].z += wgt * r0.z; acc[li][0].w += wgt * r0.w;
        acc[li][1].x += wgt * r1.x; acc[li][1].y += wgt * r1.y;
        acc[li][1].z += wgt * r1.z; acc[li][1].w += wgt * r1.w;
      }
    }
    #pragma unroll
    for (int li = 0; li < 8; ++li) {
      const float inv = ivS[8 * w + li];
      v4f* __restrict__ ab =
          (v4f*)(aligned + ((size_t)b * Lc + l0 + 8 * w + li) * Dc);
      v4f v0 = { acc[li][0].x * inv, acc[li][0].y * inv,
                 acc[li][0].z * inv, acc[li][0].w * inv };
      v4f v1 = { acc[li][1].x * inv, acc[li][1].y * inv,
                 acc[li][1].z * inv, acc[li][1].w * inv };
      __builtin_nontemporal_store(v0, ab + lane);      // 1KB/instr, contiguous
      __builtin_nontemporal_store(v1, ab + 64 + lane);
    }
  }

  // Phase C: dense attn write; literal zeros outside the per-l band.
  // Lane = (rsub, l4): wave stores 8 rows x 128B (full cache lines) = 1KB
  // per instruction. In-band test: (l-sb[t])^2 <= smin^2+200.
  {
    const int w = tid >> 6;
    const int lane = tid & 63;
    const int rsub = lane >> 3;             // 0..7 row within wave's group
    const int l4 = (lane & 7) * 4;          // 0,4,...,28
    const v4f ng = *(const v4f*)&ngS[l4];
    const v4f iv = *(const v4f*)&ivS[l4];
    const v4f th = *(const v4f*)&thS[l4];
    const float flb = (float)(l0 + l4);
    float* __restrict__ ap = attn + (size_t)b * Tc * Lc + l0 + l4;
    for (int p = 0; p < Tc / 32; ++p) {      // 16 iterations
      const int t = p * 32 + w * 8 + rsub;
      const float d0 = flb - sbS[t];
      v4f val;
      #pragma unroll
      for (int j = 0; j < 4; ++j) {
        const float s = d0 + (float)j;
        const float ss = s * s;
        val[j] = (ss <= th[j]) ? __expf(ng[j] - SIGMA * ss) * iv[j] : 0.0f;
      }
      __builtin_nontemporal_store(val, (v4f*)(ap + (size_t)t * Lc));
    }
  }
}

extern "C" void kernel_launch(void* const* d_in, const int* in_sizes, int n_in,
                              void* d_out, int out_size, void* d_ws, size_t ws_size,
                              hipStream_t stream) {
  const float* x   = (const float*)d_in[0];
  const float* dur = (const float*)d_in[1];

  float* aligned = (float*)d_out;                        // B*L*D
  float* attn    = (float*)d_out + (size_t)Bc * Lc * Dc; // B*T*L

  soft_align<<<Bc * (Lc / LT), 256, 0, stream>>>(x, dur, aligned, attn);
}

// Round 5
// 293.307 us; speedup vs baseline: 1.0857x; 1.0268x over previous
//
#include <hip/hip_runtime.h>

// B=32, T=512, D=512, L=2048. x:(B,T,D) f32, durations:(B,T) f32.
// d_out = aligned (B,L,D) f32  ||  attn (B,T,L) f32.
//
// attn column l = softmax_t of -0.2*(l-start_t)^2. Terms more than
// sqrt(smin^2+200) frames from l are < e^-40 of the max term (denom >= 1),
// i.e. < 4.3e-18 -> exact 0 in fp32 outputs and invisible in the denom.
//
// R7: single fused dispatch (in-block shfl scan; no ws) = 298us.
// R8: 3-kernel split regressed (+20us).
// R9: LT=32 geometry, one band walk per wave = 301us (neutral).
//     R6-R9 lesson: NO compute/scheduling restructure moves the kernel ->
//     the invariant is the store path.
// R10 (this round): drop __builtin_nontemporal_store -> plain stores.
//     Invariant non-fill time ~130us over 268MB stores = 2.05 TB/s, while
//     the harness fill hits 6.4 TB/s on the same buffer with plain stores.
//     Theory: gfx950 'nt' store hint throttles streaming writes ~3x.
//     Full-line coalesced plain stores do no read-for-ownership (fill's
//     FETCH_SIZE~0 proves it), so this costs no extra HBM traffic.

typedef float v4f __attribute__((ext_vector_type(4)));

static constexpr int Bc = 32;
static constexpr int Tc = 512;
static constexpr int Dc = 512;
static constexpr int Lc = 2048;
static constexpr int LT = 32;             // frames per block
static constexpr float SIGMA = 0.2f;
static constexpr float CUT2 = 200.0f;     // 40/SIGMA

// One 256-thread block per (b, 32-frame tile).
__global__ void __launch_bounds__(256, 4)
soft_align(const float* __restrict__ x,
           const float* __restrict__ dur,
           float* __restrict__ aligned,
           float* __restrict__ attn) {
  const int tid = threadIdx.x;
  const int bid = blockIdx.x;
  // XCD-chunked swizzle: 2048 blocks, 8 XCDs -> 256 per XCD = 4 consecutive b.
  const int swz = (bid & 7) * 256 + (bid >> 3);
  const int b = swz >> 6;                   // 64 tiles per b
  const int tile = swz & 63;
  const int l0 = tile * LT;

  __shared__ float sbS[Tc];                 // token start offsets
  __shared__ __align__(16) float ngS[LT];   // SIGMA*smin^2 per l
  __shared__ __align__(16) float ivS[LT];   // 1/denom per l
  __shared__ __align__(16) float thS[LT];   // smin^2 + 200 per l
  __shared__ int T0w[4], T1w[4];            // per-wave union band
  __shared__ float wsumS[4];                // per-wave duration sums (scan)

  // Fused exclusive cumsum of durations -> sbS.
  // Wave w scans elements [128w, 128w+128), 2 per lane, shfl_up scan.
  {
    const int w = tid >> 6, lane = tid & 63;
    const int e0 = 128 * w + 2 * lane;
    const float2 dv = *(const float2*)(dur + (size_t)b * Tc + e0);
    const float p = dv.x + dv.y;
    float s = p;
    #pragma unroll
    for (int off = 1; off < 64; off <<= 1) {
      const float v = __shfl_up(s, off);
      if (lane >= off) s += v;
    }
    if (lane == 63) wsumS[w] = s;
    if (tid < 4) { T0w[tid] = Tc; T1w[tid] = 0; }
    __syncthreads();
    float prefix = 0.0f;
    #pragma unroll
    for (int i = 0; i < 3; ++i) prefix += (i < w) ? wsumS[i] : 0.0f;
    sbS[e0]     = prefix + s - p;            // excl. prefix of e0
    sbS[e0 + 1] = prefix + s - dv.y;         // excl. prefix of e0+1
  }
  __syncthreads();

  // Per-l setup (32 threads): nearest start (exact softmax max), band
  // bounds by binary search, banded denom (exact in fp32).
  if (tid < LT) {
    const float fl = (float)(l0 + tid);
    int lo = 0, hi = Tc;
    while (lo < hi) { int mid = (lo + hi) >> 1; if (sbS[mid] <= fl) lo = mid + 1; else hi = mid; }
    float smin = fl - sbS[lo - 1];          // sbS[0]=0 <= fl -> lo >= 1
    if (lo < Tc) smin = fminf(smin, sbS[lo] - fl);
    const float smin2 = smin * smin;
    const float negam = SIGMA * smin2;
    const float smax = sqrtf(smin2 + CUT2);
    const float loV = fl - smax, hiV = fl + smax;
    int a = 0, c = lo;
    while (a < c) { int mid = (a + c) >> 1; if (sbS[mid] < loV) a = mid + 1; else c = mid; }
    const int bt0 = a;                      // first t with sbS[t] >= loV
    a = lo; c = Tc;
    while (a < c) { int mid = (a + c) >> 1; if (sbS[mid] <= hiV) a = mid + 1; else c = mid; }
    const int bt1 = a;                      // first t with sbS[t] > hiV
    float denom = 0.0f;
    for (int t = bt0; t < bt1; ++t) {
      const float s = fl - sbS[t];
      denom += __expf(negam - SIGMA * s * s);  // <= 1, max term = 1
    }
    ngS[tid] = negam;
    ivS[tid] = 1.0f / denom;
    thS[tid] = smin2 + CUT2;
    atomicMin(&T0w[tid >> 3], bt0);
    atomicMax(&T1w[tid >> 3], bt1);
  }
  __syncthreads();

  // Phase B: aligned gather. Wave w owns l [8w, 8w+8) x full D.
  // ONE walk of the wave-union band; lane reads 2 distinct float4 of row t
  // (2KB/wave-instr-pair, full coalescing).
  {
    const int w = tid >> 6;
    const int lane = tid & 63;
    const int Tb0 = T0w[w], Tb1 = T1w[w];
    const float4* __restrict__ xb = (const float4*)(x + (size_t)b * Tc * Dc);
    float negam_r[8];
    #pragma unroll
    for (int li = 0; li < 8; ++li) negam_r[li] = ngS[8 * w + li];
    const float flb = (float)(l0 + 8 * w);
    float4 acc[8][2] = {};
    for (int t = Tb0; t < Tb1; ++t) {
      const float4 r0 = xb[(size_t)t * (Dc / 4) + lane];
      const float4 r1 = xb[(size_t)t * (Dc / 4) + 64 + lane];
      const float d0 = flb - sbS[t];
      #pragma unroll
      for (int li = 0; li < 8; ++li) {
        const float s = d0 + (float)li;
        const float wgt = __expf(negam_r[li] - SIGMA * s * s);
        acc[li][0].x += wgt * r0.x; acc[li][0].y += wgt * r0.y;
        acc[li][0].z += wgt * r0.z; acc[li][0].w += wgt * r0.w;
        acc[li][1].x += wgt * r1.x; acc[li][1].y += wgt * r1.y;
        acc[li][1].z += wgt * r1.z; acc[li][1].w += wgt * r1.w;
      }
    }
    #pragma unroll
    for (int li = 0; li < 8; ++li) {
      const float inv = ivS[8 * w + li];
      v4f* __restrict__ ab =
          (v4f*)(aligned + ((size_t)b * Lc + l0 + 8 * w + li) * Dc);
      v4f v0 = { acc[li][0].x * inv, acc[li][0].y * inv,
                 acc[li][0].z * inv, acc[li][0].w * inv };
      v4f v1 = { acc[li][1].x * inv, acc[li][1].y * inv,
                 acc[li][1].z * inv, acc[li][1].w * inv };
      ab[lane] = v0;                         // plain store: 1KB/instr, contiguous
      ab[64 + lane] = v1;
    }
  }

  // Phase C: dense attn write; literal zeros outside the per-l band.
  // Lane = (rsub, l4): wave stores 8 rows x 128B (full cache lines) = 1KB
  // per instruction. In-band test: (l-sb[t])^2 <= smin^2+200.
  {
    const int w = tid >> 6;
    const int lane = tid & 63;
    const int rsub = lane >> 3;             // 0..7 row within wave's group
    const int l4 = (lane & 7) * 4;          // 0,4,...,28
    const v4f ng = *(const v4f*)&ngS[l4];
    const v4f iv = *(const v4f*)&ivS[l4];
    const v4f th = *(const v4f*)&thS[l4];
    const float flb = (float)(l0 + l4);
    float* __restrict__ ap = attn + (size_t)b * Tc * Lc + l0 + l4;
    for (int p = 0; p < Tc / 32; ++p) {      // 16 iterations
      const int t = p * 32 + w * 8 + rsub;
      const float d0 = flb - sbS[t];
      v4f val;
      #pragma unroll
      for (int j = 0; j < 4; ++j) {
        const float s = d0 + (float)j;
        const float ss = s * s;
        val[j] = (ss <= th[j]) ? __expf(ng[j] - SIGMA * ss) * iv[j] : 0.0f;
      }
      *(v4f*)(ap + (size_t)t * Lc) = val;    // plain store
    }
  }
}

extern "C" void kernel_launch(void* const* d_in, const int* in_sizes, int n_in,
                              void* d_out, int out_size, void* d_ws, size_t ws_size,
                              hipStream_t stream) {
  const float* x   = (const float*)d_in[0];
  const float* dur = (const float*)d_in[1];

  float* aligned = (float*)d_out;                        // B*L*D
  float* attn    = (float*)d_out + (size_t)Bc * Lc * Dc; // B*T*L

  soft_align<<<Bc * (Lc / LT), 256, 0, stream>>>(x, dur, aligned, attn);
}